// Round 17
// baseline (90.899 us; speedup 1.0000x reference)
//
#include <hip/hip_runtime.h>
#include <math.h>

typedef _Float16 half8 __attribute__((ext_vector_type(8)));
typedef _Float16 half4 __attribute__((ext_vector_type(4)));
typedef float    f32x4 __attribute__((ext_vector_type(4)));

#define TOKENS  32768
#define HIDDEN  2048
#define EXPERTS 64
#define TOPK    8
#define TB      32               // tokens per block
#define BKW     64               // k per staged window
#define NWIN    (HIDDEN / BKW)   // 32
#define LDH     72               // LDS row stride in halves (144 B: 16B-aligned)

// ---------------------------------------------------------------------------
// r16 = r15 numerics/staging/barriers, new geometry for cross-block TLP:
// 128-thr blocks (2 waves) x 32 tokens, grid 1024 -> 4-5 blocks/CU resident
// (r15: 2). Waves split each window's K (wave h = k-half, all 32 tokens, all
// 64 experts): per-wave frag reads drop 20 -> 12 b128/window and per-wave
// acc = 8 x f32x4 partials reduced across the 2 waves in the epilogue.
// A and W staged to LDS with inline fp32->hi/lo fp16 split (fp16x3 MFMA:
// hi*hi + hi*lo + lo*hi). Single-buffered, 2 barriers/window, next-window
// loads issued after publish so they fly across the compute+next-stage.
// ---------------------------------------------------------------------------
__global__ __launch_bounds__(128, 1)
void router_mfma32(const float* __restrict__ A,
                   const float* __restrict__ W,
                   const float* __restrict__ bias,
                   float* __restrict__ out) {
    __shared__ __align__(16) _Float16 hsm[(2 * TB + 2 * 64) * LDH];  // Ahi|Alo|Whi|Wlo = 27648 B
    _Float16* Ahs = hsm;                       // [32][72]
    _Float16* Als = hsm + TB * LDH;            // [32][72]
    _Float16* Whs = hsm + 2 * TB * LDH;        // [64][72]
    _Float16* Wls = hsm + 2 * TB * LDH + 64 * LDH;

    const int tid = threadIdx.x;               // 0..127
    const int h   = tid >> 6;                  // wave = k-half of each window
    const int l   = tid & 63;
    const int g   = blockIdx.x;

    // A staging map: rows (tid>>3)+16j (j=0,1), float4 chunks (tid&7)+8j2
    const int a_r = tid >> 3;                  // 0..15
    const int a_c = tid & 7;                   // 0..7
    // W staging map: row tid>>1 (0..63), 8 float4 chunks at (tid&1)*8 + j
    const int w_e = tid >> 1;
    const int w_c = (tid & 1) * 8;

    const float* Abase = A + (size_t)g * TB * HIDDEN;
    const float* WBase = W + (size_t)w_e * HIDDEN;

    f32x4 acc[2][4];                           // [token slab][expert tile]
    #pragma unroll
    for (int s = 0; s < 2; ++s)
        #pragma unroll
        for (int n = 0; n < 4; ++n) acc[s][n] = (f32x4){0.f, 0.f, 0.f, 0.f};

    float4 ar0, ar1, ar2, ar3;                 // A staging regs
    float4 wr0, wr1, wr2, wr3, wr4, wr5, wr6, wr7;  // W staging regs

    #define LOADA(win) do {                                                  \
        const float* p_ = Abase + (size_t)(win) * BKW;                       \
        ar0 = *(const float4*)(p_ + (size_t)(a_r     ) * HIDDEN + (a_c    ) * 4); \
        ar1 = *(const float4*)(p_ + (size_t)(a_r     ) * HIDDEN + (a_c + 8) * 4); \
        ar2 = *(const float4*)(p_ + (size_t)(a_r + 16) * HIDDEN + (a_c    ) * 4); \
        ar3 = *(const float4*)(p_ + (size_t)(a_r + 16) * HIDDEN + (a_c + 8) * 4); \
    } while (0)

    #define LOADW(win) do {                                                  \
        const float* q_ = WBase + (size_t)(win) * BKW + w_c * 4;             \
        wr0 = *(const float4*)(q_);      wr1 = *(const float4*)(q_ + 4);     \
        wr2 = *(const float4*)(q_ + 8);  wr3 = *(const float4*)(q_ + 12);    \
        wr4 = *(const float4*)(q_ + 16); wr5 = *(const float4*)(q_ + 20);    \
        wr6 = *(const float4*)(q_ + 24); wr7 = *(const float4*)(q_ + 28);    \
    } while (0)

    #define SPLIT4(HS, LS, v, OFF) do {                                      \
        _Float16 h0_ = (_Float16)(v).x, h1_ = (_Float16)(v).y;               \
        _Float16 h2_ = (_Float16)(v).z, h3_ = (_Float16)(v).w;               \
        half4 hh_ = {h0_, h1_, h2_, h3_};                                    \
        half4 ll_ = {(_Float16)((v).x - (float)h0_),                         \
                     (_Float16)((v).y - (float)h1_),                         \
                     (_Float16)((v).z - (float)h2_),                         \
                     (_Float16)((v).w - (float)h3_)};                        \
        *(half4*)(&(HS)[(OFF)]) = hh_;                                       \
        *(half4*)(&(LS)[(OFF)]) = ll_;                                       \
    } while (0)

    #define STAGE() do {                                                     \
        SPLIT4(Ahs, Als, ar0, (a_r     ) * LDH + (a_c    ) * 4);             \
        SPLIT4(Ahs, Als, ar1, (a_r     ) * LDH + (a_c + 8) * 4);             \
        SPLIT4(Ahs, Als, ar2, (a_r + 16) * LDH + (a_c    ) * 4);             \
        SPLIT4(Ahs, Als, ar3, (a_r + 16) * LDH + (a_c + 8) * 4);             \
        SPLIT4(Whs, Wls, wr0, w_e * LDH + (w_c    ) * 4);                    \
        SPLIT4(Whs, Wls, wr1, w_e * LDH + (w_c + 1) * 4);                    \
        SPLIT4(Whs, Wls, wr2, w_e * LDH + (w_c + 2) * 4);                    \
        SPLIT4(Whs, Wls, wr3, w_e * LDH + (w_c + 3) * 4);                    \
        SPLIT4(Whs, Wls, wr4, w_e * LDH + (w_c + 4) * 4);                    \
        SPLIT4(Whs, Wls, wr5, w_e * LDH + (w_c + 5) * 4);                    \
        SPLIT4(Whs, Wls, wr6, w_e * LDH + (w_c + 6) * 4);                    \
        SPLIT4(Whs, Wls, wr7, w_e * LDH + (w_c + 7) * 4);                    \
    } while (0)

    LOADA(0);
    LOADW(0);

    const int ko = h * 32 + (l >> 4) * 8;      // this wave's k-half frag offset

    #pragma unroll 1
    for (int win = 0; win < NWIN; ++win) {
        __syncthreads();                       // previous window fully consumed
        STAGE();
        __syncthreads();                       // window published

        if (win + 1 < NWIN) {                  // next-window loads fly during MFMA
            LOADA(win + 1);
            LOADW(win + 1);
        }

        #pragma unroll
        for (int s = 0; s < 2; ++s) {          // token slab s*16..s*16+15
            half8 ahi = *(const half8*)(&Ahs[(s * 16 + (l & 15)) * LDH + ko]);
            half8 alo = *(const half8*)(&Als[(s * 16 + (l & 15)) * LDH + ko]);
            #pragma unroll
            for (int n = 0; n < 4; ++n) {
                half8 bh = *(const half8*)(&Whs[(n * 16 + (l & 15)) * LDH + ko]);
                half8 bl = *(const half8*)(&Wls[(n * 16 + (l & 15)) * LDH + ko]);
                acc[s][n] = __builtin_amdgcn_mfma_f32_16x16x32_f16(ahi, bh, acc[s][n], 0, 0, 0);
                acc[s][n] = __builtin_amdgcn_mfma_f32_16x16x32_f16(ahi, bl, acc[s][n], 0, 0, 0);
                acc[s][n] = __builtin_amdgcn_mfma_f32_16x16x32_f16(alo, bh, acc[s][n], 0, 0, 0);
            }
        }
    }
    #undef LOADA
    #undef LOADW
    #undef SPLIT4
    #undef STAGE

    // ---- epilogue: cross-k-half reduce + bias, top-8, scatter ----
    __syncthreads();                           // staging LDS dead; alias as float
    float* lg = (float*)hsm;                   // [32 tok][68]
    float* sc = (float*)hsm + TB * 68;         // [32 tok][65]

    // D layout (verified r8): token = s*16 + (l>>4)*4 + q_, expert = n*16 + (l&15)
    if (h == 1) {
        #pragma unroll
        for (int s = 0; s < 2; ++s)
            #pragma unroll
            for (int n = 0; n < 4; ++n)
                #pragma unroll
                for (int q_ = 0; q_ < 4; ++q_)
                    lg[(s * 16 + (l >> 4) * 4 + q_) * 68 + n * 16 + (l & 15)] = acc[s][n][q_];
    }
    __syncthreads();
    if (h == 0) {
        #pragma unroll
        for (int s = 0; s < 2; ++s)
            #pragma unroll
            for (int n = 0; n < 4; ++n) {
                float b = bias[n * 16 + (l & 15)];
                #pragma unroll
                for (int q_ = 0; q_ < 4; ++q_) {
                    int idx = (s * 16 + (l >> 4) * 4 + q_) * 68 + n * 16 + (l & 15);
                    lg[idx] = lg[idx] + acc[s][n][q_] + b;
                }
            }
    }
    for (int i = tid; i < TB * 65; i += 128) sc[i] = 0.f;
    __syncthreads();

    if (tid < TB) {
        const int t = tid;
        float v[64];
        #pragma unroll
        for (int e = 0; e < 64; ++e) v[e] = lg[t * 68 + e];

        float tvals[TOPK]; int tix[TOPK]; float probs[TOPK];
        unsigned long long chosen = 0ull;
        #pragma unroll
        for (int j = 0; j < TOPK; ++j) {
            float best = -INFINITY; int bi = 0;
            #pragma unroll
            for (int e = 0; e < 64; ++e) {
                bool ok = ((chosen >> e) & 1ull) == 0ull;
                if (ok && v[e] > best) { best = v[e]; bi = e; }  // strict >: lowest idx on tie
            }
            chosen |= (1ull << bi);
            tvals[j] = best; tix[j] = bi;
        }
        float m = tvals[0];
        float ssum = 0.f;
        #pragma unroll
        for (int j = 0; j < TOPK; ++j) { probs[j] = __expf(tvals[j] - m); ssum += probs[j]; }
        float inv = 1.f / ssum;
        #pragma unroll
        for (int j = 0; j < TOPK; ++j) probs[j] *= inv;

        #pragma unroll
        for (int j = 0; j < TOPK; ++j) sc[t * 65 + tix[j]] = probs[j];

        float* oidx = out + (size_t)TOKENS * EXPERTS;
        const int token = g * TB + t;
        #pragma unroll
        for (int j = 0; j < TOPK; ++j) oidx[(size_t)token * TOPK + j] = (float)tix[j];
    }
    __syncthreads();

    // ---- coalesced score write: 32 tokens x 64 experts = 512 float4 ----
    float* oscore = out + (size_t)g * (TB * 64);
    #pragma unroll
    for (int p = 0; p < 4; ++p) {
        int fi  = tid + 128 * p;               // float4 index 0..511
        int tok = fi >> 4;
        int es  = (fi & 15) * 4;
        float4 vv;
        vv.x = sc[tok * 65 + es + 0];
        vv.y = sc[tok * 65 + es + 1];
        vv.z = sc[tok * 65 + es + 2];
        vv.w = sc[tok * 65 + es + 3];
        *(float4*)(oscore + (size_t)fi * 4) = vv;
    }
}

extern "C" void kernel_launch(void* const* d_in, const int* in_sizes, int n_in,
                              void* d_out, int out_size, void* d_ws, size_t ws_size,
                              hipStream_t stream) {
    const float* A    = (const float*)d_in[0];   // [32768, 2048] fp32
    const float* W    = (const float*)d_in[1];   // [64, 2048] fp32
    const float* bias = (const float*)d_in[2];   // [64] fp32
    float* out = (float*)d_out;                  // scores (32768*64) ++ idx (32768*8)
    (void)d_ws; (void)ws_size;

    router_mfma32<<<TOKENS / TB, 128, 0, stream>>>(A, W, bias, out);
}

// Round 18
// 65.491 us; speedup vs baseline: 1.3880x; 1.3880x over previous
//
#include <hip/hip_runtime.h>
#include <math.h>

typedef _Float16 half8 __attribute__((ext_vector_type(8)));
typedef _Float16 half4 __attribute__((ext_vector_type(4)));
typedef float    f32x4 __attribute__((ext_vector_type(4)));

#define TOKENS  32768
#define HIDDEN  2048
#define EXPERTS 64
#define TOPK    8
#define BKW     128              // k per staged window (r17: 64 -> 128)
#define NWIN    (HIDDEN / BKW)   // 16
#define LDH     136              // LDS row stride in halves (272 B: 16B-aligned)

// ---------------------------------------------------------------------------
// r17 = r15 (best, 61.2us) with BKW doubled to 128: halves barrier count and
// serial-STAGE section count; loads fly ~2400cyc (>> 900 HBM). All else
// identical: fused single kernel, fp16x3 split (hi*hi+hi*lo+lo*hi, fp32 acc),
// block = 256 thr (4 waves) owns 64 tokens x 64 experts x full K; wave =
// 16-token slab; A and W staged to LDS with inline fp32->hi/lo conversion,
// single-buffered, 2 barriers/window. Frag layouts verified (r8/r10).
// ---------------------------------------------------------------------------
__global__ __launch_bounds__(256, 1)
void router_mfma(const float* __restrict__ A,
                 const float* __restrict__ W,
                 const float* __restrict__ bias,
                 float* __restrict__ out) {
    __shared__ __align__(16) _Float16 hsm[4 * 64 * LDH];   // Ahi|Alo|Whi|Wlo = 69632 B
    _Float16* Ahs = hsm;
    _Float16* Als = hsm + 64 * LDH;
    _Float16* Whs = hsm + 2 * 64 * LDH;
    _Float16* Wls = hsm + 3 * 64 * LDH;

    const int tid = threadIdx.x;
    const int w   = tid >> 6;          // wave = 16-token slab
    const int l   = tid & 63;
    const int g   = blockIdx.x;

    // A staging map: 4 row-rounds x 2 column-halves; per instr 16 lanes cover
    // 256 B contiguous of one row (same pattern as r15).
    const int s_tok = tid >> 4;        // 0..15
    const int s_c   = tid & 15;        // float4 chunk within column-half
    // W staging map: row we = tid>>2, float4 chunks (tid&3) + 4j (j=0..7)
    const int we = tid >> 2;           // 0..63
    const int wq = tid & 3;

    const float* Abase = A + (size_t)g * 64 * HIDDEN;
    const float* WBase = W + (size_t)we * HIDDEN;

    f32x4 acc[4];
    #pragma unroll
    for (int n = 0; n < 4; ++n) acc[n] = (f32x4){0.f, 0.f, 0.f, 0.f};

    float4 ar0, ar1, ar2, ar3, ar4, ar5, ar6, ar7;   // A: rows {0,16,32,48} x halves {0,1}
    float4 wr0, wr1, wr2, wr3, wr4, wr5, wr6, wr7;   // W: 8 chunks of own row

    #define LOADA(win) do {                                                  \
        const float* p_ = Abase + (size_t)(win) * BKW + s_c * 4;             \
        ar0 = *(const float4*)(p_ + (size_t)(s_tok     ) * HIDDEN);          \
        ar1 = *(const float4*)(p_ + (size_t)(s_tok     ) * HIDDEN + 64);     \
        ar2 = *(const float4*)(p_ + (size_t)(s_tok + 16) * HIDDEN);          \
        ar3 = *(const float4*)(p_ + (size_t)(s_tok + 16) * HIDDEN + 64);     \
        ar4 = *(const float4*)(p_ + (size_t)(s_tok + 32) * HIDDEN);          \
        ar5 = *(const float4*)(p_ + (size_t)(s_tok + 32) * HIDDEN + 64);     \
        ar6 = *(const float4*)(p_ + (size_t)(s_tok + 48) * HIDDEN);          \
        ar7 = *(const float4*)(p_ + (size_t)(s_tok + 48) * HIDDEN + 64);     \
    } while (0)

    #define LOADW(win) do {                                                  \
        const float* q_ = WBase + (size_t)(win) * BKW + wq * 4;              \
        wr0 = *(const float4*)(q_);       wr1 = *(const float4*)(q_ + 16);   \
        wr2 = *(const float4*)(q_ + 32);  wr3 = *(const float4*)(q_ + 48);   \
        wr4 = *(const float4*)(q_ + 64);  wr5 = *(const float4*)(q_ + 80);   \
        wr6 = *(const float4*)(q_ + 96);  wr7 = *(const float4*)(q_ + 112);  \
    } while (0)

    // split one float4 into hi/lo half4 and store at half-offset OFF
    #define SPLIT4(HS, LS, v, OFF) do {                                      \
        _Float16 h0_ = (_Float16)(v).x, h1_ = (_Float16)(v).y;               \
        _Float16 h2_ = (_Float16)(v).z, h3_ = (_Float16)(v).w;               \
        half4 hh_ = {h0_, h1_, h2_, h3_};                                    \
        half4 ll_ = {(_Float16)((v).x - (float)h0_),                         \
                     (_Float16)((v).y - (float)h1_),                         \
                     (_Float16)((v).z - (float)h2_),                         \
                     (_Float16)((v).w - (float)h3_)};                        \
        *(half4*)(&(HS)[(OFF)]) = hh_;                                       \
        *(half4*)(&(LS)[(OFF)]) = ll_;                                       \
    } while (0)

    #define STAGE() do {                                                     \
        SPLIT4(Ahs, Als, ar0, (s_tok     ) * LDH + s_c * 4);                 \
        SPLIT4(Ahs, Als, ar1, (s_tok     ) * LDH + 64 + s_c * 4);            \
        SPLIT4(Ahs, Als, ar2, (s_tok + 16) * LDH + s_c * 4);                 \
        SPLIT4(Ahs, Als, ar3, (s_tok + 16) * LDH + 64 + s_c * 4);            \
        SPLIT4(Ahs, Als, ar4, (s_tok + 32) * LDH + s_c * 4);                 \
        SPLIT4(Ahs, Als, ar5, (s_tok + 32) * LDH + 64 + s_c * 4);            \
        SPLIT4(Ahs, Als, ar6, (s_tok + 48) * LDH + s_c * 4);                 \
        SPLIT4(Ahs, Als, ar7, (s_tok + 48) * LDH + 64 + s_c * 4);            \
        SPLIT4(Whs, Wls, wr0, we * LDH + wq * 4);                            \
        SPLIT4(Whs, Wls, wr1, we * LDH + wq * 4 + 16);                       \
        SPLIT4(Whs, Wls, wr2, we * LDH + wq * 4 + 32);                       \
        SPLIT4(Whs, Wls, wr3, we * LDH + wq * 4 + 48);                       \
        SPLIT4(Whs, Wls, wr4, we * LDH + wq * 4 + 64);                       \
        SPLIT4(Whs, Wls, wr5, we * LDH + wq * 4 + 80);                       \
        SPLIT4(Whs, Wls, wr6, we * LDH + wq * 4 + 96);                       \
        SPLIT4(Whs, Wls, wr7, we * LDH + wq * 4 + 112);                      \
    } while (0)

    LOADA(0);
    LOADW(0);

    #pragma unroll 1
    for (int win = 0; win < NWIN; ++win) {
        __syncthreads();                       // previous window fully consumed
        STAGE();
        __syncthreads();                       // window published

        if (win + 1 < NWIN) {                  // next-window loads fly during MFMA
            LOADA(win + 1);
            LOADW(win + 1);
        }

        #pragma unroll
        for (int ks = 0; ks < 4; ++ks) {       // 4 k-slices of 32
            const int ko = ks * 32 + (l >> 4) * 8;
            half8 ahi = *(const half8*)(&Ahs[(w * 16 + (l & 15)) * LDH + ko]);
            half8 alo = *(const half8*)(&Als[(w * 16 + (l & 15)) * LDH + ko]);
            #pragma unroll
            for (int n = 0; n < 4; ++n) {
                half8 bh = *(const half8*)(&Whs[(n * 16 + (l & 15)) * LDH + ko]);
                half8 bl = *(const half8*)(&Wls[(n * 16 + (l & 15)) * LDH + ko]);
                acc[n] = __builtin_amdgcn_mfma_f32_16x16x32_f16(ahi, bh, acc[n], 0, 0, 0);
                acc[n] = __builtin_amdgcn_mfma_f32_16x16x32_f16(ahi, bl, acc[n], 0, 0, 0);
                acc[n] = __builtin_amdgcn_mfma_f32_16x16x32_f16(alo, bh, acc[n], 0, 0, 0);
            }
        }
    }
    #undef LOADA
    #undef LOADW
    #undef SPLIT4
    #undef STAGE

    // ---- epilogue: logits (+bias) to LDS, top-8 + softmax + scatter ----
    __syncthreads();                           // staging LDS dead; alias as float
    float* lg = (float*)hsm;                   // [64 tok][68]
    float* sc = (float*)hsm + 64 * 68;         // [64 tok][65]

    // D layout (verified r8): token row = (l>>4)*4+q, expert col = n*16+(l&15)
    #pragma unroll
    for (int n = 0; n < 4; ++n) {
        float b = bias[n * 16 + (l & 15)];
        #pragma unroll
        for (int q = 0; q < 4; ++q) {
            int trow = w * 16 + (l >> 4) * 4 + q;
            lg[trow * 68 + n * 16 + (l & 15)] = acc[n][q] + b;
        }
    }
    for (int i = tid; i < 64 * 65; i += 256) sc[i] = 0.f;
    __syncthreads();

    if (tid < 64) {
        const int t = tid;
        float v[64];
        #pragma unroll
        for (int e = 0; e < 64; ++e) v[e] = lg[t * 68 + e];

        float tvals[TOPK]; int tix[TOPK]; float probs[TOPK];
        unsigned long long chosen = 0ull;
        #pragma unroll
        for (int j = 0; j < TOPK; ++j) {
            float best = -INFINITY; int bi = 0;
            #pragma unroll
            for (int e = 0; e < 64; ++e) {
                bool ok = ((chosen >> e) & 1ull) == 0ull;
                if (ok && v[e] > best) { best = v[e]; bi = e; }  // strict >: lowest idx on tie
            }
            chosen |= (1ull << bi);
            tvals[j] = best; tix[j] = bi;
        }
        float m = tvals[0];
        float ssum = 0.f;
        #pragma unroll
        for (int j = 0; j < TOPK; ++j) { probs[j] = __expf(tvals[j] - m); ssum += probs[j]; }
        float inv = 1.f / ssum;
        #pragma unroll
        for (int j = 0; j < TOPK; ++j) probs[j] *= inv;

        #pragma unroll
        for (int j = 0; j < TOPK; ++j) sc[t * 65 + tix[j]] = probs[j];

        float* oidx = out + (size_t)TOKENS * EXPERTS;
        const int token = g * 64 + t;
        #pragma unroll
        for (int j = 0; j < TOPK; ++j) oidx[(size_t)token * TOPK + j] = (float)tix[j];
    }
    __syncthreads();

    // ---- coalesced score write: 64 tokens x 64 experts = 1024 float4 ----
    float* oscore = out + (size_t)g * 4096;
    #pragma unroll
    for (int p = 0; p < 4; ++p) {
        int fi  = tid + 256 * p;               // float4 index 0..1023
        int tok = fi >> 4;
        int es  = (fi & 15) * 4;
        float4 vv;
        vv.x = sc[tok * 65 + es + 0];
        vv.y = sc[tok * 65 + es + 1];
        vv.z = sc[tok * 65 + es + 2];
        vv.w = sc[tok * 65 + es + 3];
        *(float4*)(oscore + (size_t)fi * 4) = vv;
    }
}

extern "C" void kernel_launch(void* const* d_in, const int* in_sizes, int n_in,
                              void* d_out, int out_size, void* d_ws, size_t ws_size,
                              hipStream_t stream) {
    const float* A    = (const float*)d_in[0];   // [32768, 2048] fp32
    const float* W    = (const float*)d_in[1];   // [64, 2048] fp32
    const float* bias = (const float*)d_in[2];   // [64] fp32
    float* out = (float*)d_out;                  // scores (32768*64) ++ idx (32768*8)
    (void)d_ws; (void)ws_size;

    router_mfma<<<TOKENS / 64, 256, 0, stream>>>(A, W, bias, out);
}